// Round 8
// baseline (325.067 us; speedup 1.0000x reference)
//
#include <hip/hip_runtime.h>
#include <hip/hip_bf16.h>
#include <cmath>

#define NN 8192
#define FIN 256
#define FOUT 128
#define ROWS 32
#define NCH 4
#define JC (NN / NCH)        // 2048 j per chunk
#define NWIN 8               // windows per wave (32 windows per chunk / 4 waves)

typedef short short8 __attribute__((ext_vector_type(8)));
typedef float f32x16 __attribute__((ext_vector_type(16)));
typedef unsigned long long u64;

static __device__ __forceinline__ unsigned short f2bf(float f) {
    unsigned u = __float_as_uint(f);
    u += 0x7fffu + ((u >> 16) & 1u);
    return (unsigned short)(u >> 16);
}

// ---------------------------------------------------------------------------
// Compress: adj (256MB int32) -> bm3 (8MB u64 masks) in pass_b-native layout.
// bm3[(ib*4+ch)*1024 + r*32 + winc]: ib=i>>5, r=i&31, ch=chunk, winc=window
// within chunk. Word bit (16c+q) <-> col win*64 + 4q + c.
// Thread reads 256B contiguous (one window of one row); no cross-lane ops.
// ---------------------------------------------------------------------------
__global__ __launch_bounds__(256)
void gat_compress(const int* __restrict__ adj, u64* __restrict__ bm3) {
    const int t = threadIdx.x;
    const int row = blockIdx.x * 2 + (t >> 7);
    const int wing = t & 127;                       // global window index
    const int4* p = (const int4*)(adj + (size_t)row * NN + wing * 64);
    u64 m = 0;
    #pragma unroll
    for (int q = 0; q < 16; ++q) {
        const int4 v = p[q];
        m |= (u64)(v.x > 0) << q;
        m |= (u64)(v.y > 0) << (16 + q);
        m |= (u64)(v.z > 0) << (32 + q);
        m |= (u64)(v.w > 0) << (48 + q);
    }
    const int ib = row >> 5, r = row & 31, ch = wing >> 5, winc = wing & 31;
    bm3[((size_t)(ib * 4 + ch)) * 1024 + r * 32 + winc] = m;
}

// ---------------------------------------------------------------------------
// Pass A: h = input @ W^T + Wb (bf16 MFMA). Writes hT3 in EXACT MFMA A-frag
// order: hT3[tile][fg][ks][lane][e] = h[fg*32+(lane&31)][tile*64+ks*16+(lane>>5)*8+e]
// so pass_b frag loads are 64-lane-contiguous 1KB. Also s = h·a1, t = h·a2+ab.
// ---------------------------------------------------------------------------
__global__ __launch_bounds__(256, 2)
void gat_pass_a(const float* __restrict__ input, const float* __restrict__ W,
                const float* __restrict__ Wb, const float* __restrict__ aw,
                const float* __restrict__ ab, unsigned short* __restrict__ hT3,
                float* __restrict__ s_out, float* __restrict__ t_out) {
    const int tid = threadIdx.x;
    const int w = tid >> 6, l = tid & 63;
    const int l5 = l >> 5, l31 = l & 31;
    const int nt = w >> 1, mh = w & 1;
    const int bx = blockIdx.x;
    const int i = bx * 64 + nt * 32 + l31;

    f32x16 acc0 = {}; f32x16 acc1 = {};
    #pragma unroll
    for (int ks = 0; ks < FIN / 16; ++ks) {
        const int c0 = ks * 16 + l5 * 8;
        const float4 b0 = *(const float4*)(input + (size_t)i * FIN + c0);
        const float4 b1 = *(const float4*)(input + (size_t)i * FIN + c0 + 4);
        short8 bf;
        bf[0]=(short)f2bf(b0.x); bf[1]=(short)f2bf(b0.y); bf[2]=(short)f2bf(b0.z); bf[3]=(short)f2bf(b0.w);
        bf[4]=(short)f2bf(b1.x); bf[5]=(short)f2bf(b1.y); bf[6]=(short)f2bf(b1.z); bf[7]=(short)f2bf(b1.w);
        {
            const int kcol = l31 + 32 * (2 * mh + 0);
            const float4 a0 = *(const float4*)(W + (size_t)kcol * FIN + c0);
            const float4 a1 = *(const float4*)(W + (size_t)kcol * FIN + c0 + 4);
            short8 af;
            af[0]=(short)f2bf(a0.x); af[1]=(short)f2bf(a0.y); af[2]=(short)f2bf(a0.z); af[3]=(short)f2bf(a0.w);
            af[4]=(short)f2bf(a1.x); af[5]=(short)f2bf(a1.y); af[6]=(short)f2bf(a1.z); af[7]=(short)f2bf(a1.w);
            acc0 = __builtin_amdgcn_mfma_f32_32x32x16_bf16(af, bf, acc0, 0, 0, 0);
        }
        {
            const int kcol = l31 + 32 * (2 * mh + 1);
            const float4 a0 = *(const float4*)(W + (size_t)kcol * FIN + c0);
            const float4 a1 = *(const float4*)(W + (size_t)kcol * FIN + c0 + 4);
            short8 af;
            af[0]=(short)f2bf(a0.x); af[1]=(short)f2bf(a0.y); af[2]=(short)f2bf(a0.z); af[3]=(short)f2bf(a0.w);
            af[4]=(short)f2bf(a1.x); af[5]=(short)f2bf(a1.y); af[6]=(short)f2bf(a1.z); af[7]=(short)f2bf(a1.w);
            acc1 = __builtin_amdgcn_mfma_f32_32x32x16_bf16(af, bf, acc1, 0, 0, 0);
        }
    }
    __shared__ float sred[4][32];
    __shared__ float tred[4][32];
    float sacc = 0.f, tacc = 0.f;
    const int jloc = nt * 32 + l31;
    const int ksb = jloc >> 4;
    const int lane_j = 32 * ((jloc >> 3) & 1);
    const int e = jloc & 7;
    #pragma unroll
    for (int m = 0; m < 2; ++m) {
        #pragma unroll
        for (int r = 0; r < 16; ++r) {
            const int kcol = 32 * (2 * mh + m) + 4 * l5 + (r & 3) + 8 * (r >> 2);
            const float hv = (m ? acc1[r] : acc0[r]) + Wb[kcol];
            const int fg = kcol >> 5;
            const int lane = (kcol & 31) + lane_j;
            hT3[((((size_t)bx * 4 + fg) * 4 + ksb) * 64 + lane) * 8 + e] = f2bf(hv);
            sacc += hv * aw[kcol];
            tacc += hv * aw[FOUT + kcol];
        }
    }
    sacc += __shfl_xor(sacc, 32);
    tacc += __shfl_xor(tacc, 32);
    if (l < 32) { sred[w][l] = sacc; tred[w][l] = tacc; }
    __syncthreads();
    if (mh == 0 && l < 32) {
        s_out[i] = sred[w][l] + sred[w + 1][l];
        t_out[i] = tred[w][l] + tred[w + 1][l] + ab[0];
    }
}

// ---------------------------------------------------------------------------
// Pass B (compute-only): masks preloaded from bm3 into 4 int4 registers per
// lane (64B; no LDS, no ballots, no main-loop barriers). exp -> bf16 -> MFMA
// with coalesced hT3 frags. Epilogue: cross-wave LDS reduce, coalesced writes.
// ---------------------------------------------------------------------------
__global__ __launch_bounds__(256, 4)
void gat_pass_b(const u64* __restrict__ bm3, const unsigned short* __restrict__ hT3,
                const float* __restrict__ s_in, const float* __restrict__ t_in,
                float* __restrict__ numw, float* __restrict__ dpart) {
    __shared__ float red[FOUT * ROWS];       // 16 KB
    __shared__ float denb[4][ROWS];          // 512 B
    const int tid = threadIdx.x;
    const int wv = tid >> 6, l = tid & 63;
    const int l5 = l >> 5, l31 = l & 31;
    const int i0 = blockIdx.x * ROWS;
    const int chunk = blockIdx.y;
    const int jb = chunk * JC;
    const float si = s_in[i0 + l31];

    // masks for this lane's row (l31) and this wave's 8 windows
    const u64* mbase = bm3 + ((size_t)(i0 >> 5) * 4 + chunk) * 1024
                     + (size_t)l31 * 32 + wv * NWIN;
    const int4 Rm0 = ((const int4*)mbase)[0];
    const int4 Rm1 = ((const int4*)mbase)[1];
    const int4 Rm2 = ((const int4*)mbase)[2];
    const int4 Rm3 = ((const int4*)mbase)[3];

    f32x16 acc0 = {}, acc1 = {}, acc2 = {}, acc3 = {};
    float dacc = 0.f;

    #pragma unroll
    for (int w = 0; w < NWIN; ++w) {
        const int4 pair = (w >> 1) == 0 ? Rm0 : (w >> 1) == 1 ? Rm1
                        : (w >> 1) == 2 ? Rm2 : Rm3;
        const u64 myw = (w & 1)
            ? (((u64)(unsigned)pair.z) | (((u64)(unsigned)pair.w) << 32))
            : (((u64)(unsigned)pair.x) | (((u64)(unsigned)pair.y) << 32));
        const int win = wv * NWIN + w;
        const int jw = jb + win * 64;
        const int tile = jw >> 6;
        #pragma unroll
        for (int ks = 0; ks < 4; ++ks) {
            const int jsl = jw + ks * 16 + l5 * 8;
            const float4 t0 = *(const float4*)(t_in + jsl);
            const float4 t1 = *(const float4*)(t_in + jsl + 4);
            const u64 m = myw >> (ks * 4 + l5 * 2);
            short8 bf;
            float x, p;
            x = si + t0.x; x = fmaxf(x, 0.2f * x); p = __expf(x);
            p = ((m >> 0)  & 1ull) ? p : 0.f; dacc += p; bf[0] = (short)f2bf(p);
            x = si + t0.y; x = fmaxf(x, 0.2f * x); p = __expf(x);
            p = ((m >> 16) & 1ull) ? p : 0.f; dacc += p; bf[1] = (short)f2bf(p);
            x = si + t0.z; x = fmaxf(x, 0.2f * x); p = __expf(x);
            p = ((m >> 32) & 1ull) ? p : 0.f; dacc += p; bf[2] = (short)f2bf(p);
            x = si + t0.w; x = fmaxf(x, 0.2f * x); p = __expf(x);
            p = ((m >> 48) & 1ull) ? p : 0.f; dacc += p; bf[3] = (short)f2bf(p);
            x = si + t1.x; x = fmaxf(x, 0.2f * x); p = __expf(x);
            p = ((m >> 1)  & 1ull) ? p : 0.f; dacc += p; bf[4] = (short)f2bf(p);
            x = si + t1.y; x = fmaxf(x, 0.2f * x); p = __expf(x);
            p = ((m >> 17) & 1ull) ? p : 0.f; dacc += p; bf[5] = (short)f2bf(p);
            x = si + t1.z; x = fmaxf(x, 0.2f * x); p = __expf(x);
            p = ((m >> 33) & 1ull) ? p : 0.f; dacc += p; bf[6] = (short)f2bf(p);
            x = si + t1.w; x = fmaxf(x, 0.2f * x); p = __expf(x);
            p = ((m >> 49) & 1ull) ? p : 0.f; dacc += p; bf[7] = (short)f2bf(p);

            const unsigned short* hp =
                hT3 + (((size_t)tile * 4) * 4 + ks) * 512 + (size_t)l * 8;
            const short8 af0 = *(const short8*)(hp);
            const short8 af1 = *(const short8*)(hp + 2048);
            const short8 af2 = *(const short8*)(hp + 4096);
            const short8 af3 = *(const short8*)(hp + 6144);
            acc0 = __builtin_amdgcn_mfma_f32_32x32x16_bf16(af0, bf, acc0, 0, 0, 0);
            acc1 = __builtin_amdgcn_mfma_f32_32x32x16_bf16(af1, bf, acc1, 0, 0, 0);
            acc2 = __builtin_amdgcn_mfma_f32_32x32x16_bf16(af2, bf, acc2, 0, 0, 0);
            acc3 = __builtin_amdgcn_mfma_f32_32x32x16_bf16(af3, bf, acc3, 0, 0, 0);
        }
    }

    // ---------- epilogue: cross-wave reduction (j-split partials) ----------
    #pragma unroll
    for (int ph = 0; ph < 4; ++ph) {
        __syncthreads();
        if (wv == ph) {
            #pragma unroll
            for (int r = 0; r < 16; ++r) {
                const int fr = (r & 3) + 8 * (r >> 2) + 4 * l5;
                if (ph == 0) {
                    red[(fr     ) * ROWS + l31] = acc0[r];
                    red[(fr + 32) * ROWS + l31] = acc1[r];
                    red[(fr + 64) * ROWS + l31] = acc2[r];
                    red[(fr + 96) * ROWS + l31] = acc3[r];
                } else {
                    red[(fr     ) * ROWS + l31] += acc0[r];
                    red[(fr + 32) * ROWS + l31] += acc1[r];
                    red[(fr + 64) * ROWS + l31] += acc2[r];
                    red[(fr + 96) * ROWS + l31] += acc3[r];
                }
            }
        }
    }
    dacc += __shfl_xor(dacc, 32);
    if (l5 == 0) denb[wv][l31] = dacc;
    __syncthreads();

    float* nb = numw + (size_t)chunk * FOUT * NN;
    #pragma unroll
    for (int e = 0; e < 4; ++e) {
        const int f = e * 32 + (tid >> 3);
        const int io = (tid & 7) * 4;
        *(float4*)(nb + (size_t)f * NN + i0 + io) = *(const float4*)(red + f * ROWS + io);
    }
    if (tid < ROWS)
        dpart[(size_t)chunk * NN + i0 + tid] =
            denb[0][tid] + denb[1][tid] + denb[2][tid] + denb[3][tid];
}

// ---------------------------------------------------------------------------
// Pass C: out[i][f] = elu( sum_c numw[c][f][i] / sum_c dpart[c][i] )
// ---------------------------------------------------------------------------
__global__ __launch_bounds__(256)
void gat_reduce(const float* __restrict__ numw, const float* __restrict__ dpart,
                float* __restrict__ out, int nchunk) {
    __shared__ float tile[FOUT * 33];
    __shared__ float dent[32];
    const int t = threadIdx.x;
    const int i0 = blockIdx.x * 32;
    if (t < 32) {
        float d = 0.f;
        for (int c = 0; c < nchunk; ++c) d += dpart[(size_t)c * NN + i0 + t];
        dent[t] = d;
    }
    __syncthreads();
    #pragma unroll
    for (int e = 0; e < 4; ++e) {
        const int f = e * 32 + (t >> 3);
        const int io = (t & 7) * 4;
        float4 s = {0.f, 0.f, 0.f, 0.f};
        for (int c = 0; c < nchunk; ++c) {
            const float4 v = *(const float4*)(numw + ((size_t)c * FOUT + f) * NN + i0 + io);
            s.x += v.x; s.y += v.y; s.z += v.z; s.w += v.w;
        }
        float v;
        v = s.x / dent[io + 0]; tile[f * 33 + io + 0] = (v > 0.f) ? v : expm1f(v);
        v = s.y / dent[io + 1]; tile[f * 33 + io + 1] = (v > 0.f) ? v : expm1f(v);
        v = s.z / dent[io + 2]; tile[f * 33 + io + 2] = (v > 0.f) ? v : expm1f(v);
        v = s.w / dent[io + 3]; tile[f * 33 + io + 3] = (v > 0.f) ? v : expm1f(v);
    }
    __syncthreads();
    #pragma unroll
    for (int e = 0; e < 4; ++e) {
        const int row = (t >> 5) * 4 + e;
        const int fo = (t & 31) * 4;
        const float4 v = { tile[(fo + 0) * 33 + row], tile[(fo + 1) * 33 + row],
                           tile[(fo + 2) * 33 + row], tile[(fo + 3) * 33 + row] };
        *(float4*)(out + (size_t)(i0 + row) * FOUT + fo) = v;
    }
}

// ---------------------------------------------------------------------------
extern "C" void kernel_launch(void* const* d_in, const int* in_sizes, int n_in,
                              void* d_out, int out_size, void* d_ws, size_t ws_size,
                              hipStream_t stream) {
    const float* input = (const float*)d_in[0];
    const int*   adj   = (const int*)d_in[1];
    const float* Ww    = (const float*)d_in[2];
    const float* Wb    = (const float*)d_in[3];
    const float* aw    = (const float*)d_in[4];
    const float* ab    = (const float*)d_in[5];
    float* out = (float*)d_out;

    char* ws = (char*)d_ws;
    unsigned short* hT3 = (unsigned short*)ws;               // 2 MB
    float* s_buf = (float*)(ws + (size_t)FOUT * NN * 2);     // 32 KB
    float* t_buf = s_buf + NN;                               // 32 KB
    float* dpart = t_buf + NN;                               // NCH*32 KB
    float* numw = dpart + (size_t)NCH * NN;                  // NCH*4 MB
    u64* bm3 = (u64*)(numw + (size_t)NCH * NN * FOUT);       // 8 MB

    gat_pass_a<<<dim3(NN / 64), 256, 0, stream>>>(input, Ww, Wb, aw, ab, hT3, s_buf, t_buf);
    gat_compress<<<dim3(NN / 2), 256, 0, stream>>>(adj, bm3);
    gat_pass_b<<<dim3(NN / ROWS, NCH), 256, 0, stream>>>(bm3, hT3, s_buf, t_buf, numw, dpart);
    gat_reduce<<<dim3(NN / 32), 256, 0, stream>>>(numw, dpart, out, NCH);
}

// Round 9
// 236.207 us; speedup vs baseline: 1.3762x; 1.3762x over previous
//
#include <hip/hip_runtime.h>
#include <hip/hip_bf16.h>
#include <cmath>

#define NN 8192
#define FIN 256
#define FOUT 128
#define ROWS 32
#define NCH 8
#define JC (NN / NCH)        // 1024 j per chunk
#define WPC (JC / 64)        // 16 windows per chunk
#define NWIN (WPC / 4)       // 4 windows per wave

typedef short short8 __attribute__((ext_vector_type(8)));
typedef float f32x16 __attribute__((ext_vector_type(16)));
typedef unsigned long long u64;

static __device__ __forceinline__ unsigned short f2bf(float f) {
    unsigned u = __float_as_uint(f);
    u += 0x7fffu + ((u >> 16) & 1u);
    return (unsigned short)(u >> 16);
}

// ---------------------------------------------------------------------------
// Compress: adj (256MB int32) -> bm3 (8MB u64 masks), pass_b-native layout.
// bm3[((row>>5)*NCH + ch)*512 + (row&31)*WPC + winc], word bit (16c+q) <->
// col (ch*WPC+winc)*64 + 4q + c. Each thread reads 256B contiguous.
// ---------------------------------------------------------------------------
__global__ __launch_bounds__(256)
void gat_compress(const int* __restrict__ adj, u64* __restrict__ bm3) {
    const int t = threadIdx.x;
    const int row = blockIdx.x * 2 + (t >> 7);
    const int wing = t & 127;                       // global window index
    const int4* p = (const int4*)(adj + (size_t)row * NN + wing * 64);
    u64 m = 0;
    #pragma unroll
    for (int q = 0; q < 16; ++q) {
        const int4 v = p[q];
        m |= (u64)(v.x > 0) << q;
        m |= (u64)(v.y > 0) << (16 + q);
        m |= (u64)(v.z > 0) << (32 + q);
        m |= (u64)(v.w > 0) << (48 + q);
    }
    const int ib = row >> 5, r = row & 31, ch = wing >> 4, winc = wing & 15;
    bm3[((size_t)(ib * NCH + ch)) * (32 * WPC) + r * WPC + winc] = m;
}

// ---------------------------------------------------------------------------
// Pass A: h = input @ W^T + Wb (bf16 MFMA). Writes hT3 in EXACT MFMA A-frag
// order: hT3[tile][fg][ks][lane][e] = h[fg*32+(lane&31)][tile*64+ks*16+(lane>>5)*8+e]
// so pass_b frag loads are 64-lane-contiguous 1KB. Also s = h·a1, t = h·a2+ab.
// ---------------------------------------------------------------------------
__global__ __launch_bounds__(256, 2)
void gat_pass_a(const float* __restrict__ input, const float* __restrict__ W,
                const float* __restrict__ Wb, const float* __restrict__ aw,
                const float* __restrict__ ab, unsigned short* __restrict__ hT3,
                float* __restrict__ s_out, float* __restrict__ t_out) {
    const int tid = threadIdx.x;
    const int w = tid >> 6, l = tid & 63;
    const int l5 = l >> 5, l31 = l & 31;
    const int nt = w >> 1, mh = w & 1;
    const int bx = blockIdx.x;
    const int i = bx * 64 + nt * 32 + l31;

    f32x16 acc0 = {}; f32x16 acc1 = {};
    #pragma unroll
    for (int ks = 0; ks < FIN / 16; ++ks) {
        const int c0 = ks * 16 + l5 * 8;
        const float4 b0 = *(const float4*)(input + (size_t)i * FIN + c0);
        const float4 b1 = *(const float4*)(input + (size_t)i * FIN + c0 + 4);
        short8 bf;
        bf[0]=(short)f2bf(b0.x); bf[1]=(short)f2bf(b0.y); bf[2]=(short)f2bf(b0.z); bf[3]=(short)f2bf(b0.w);
        bf[4]=(short)f2bf(b1.x); bf[5]=(short)f2bf(b1.y); bf[6]=(short)f2bf(b1.z); bf[7]=(short)f2bf(b1.w);
        {
            const int kcol = l31 + 32 * (2 * mh + 0);
            const float4 a0 = *(const float4*)(W + (size_t)kcol * FIN + c0);
            const float4 a1 = *(const float4*)(W + (size_t)kcol * FIN + c0 + 4);
            short8 af;
            af[0]=(short)f2bf(a0.x); af[1]=(short)f2bf(a0.y); af[2]=(short)f2bf(a0.z); af[3]=(short)f2bf(a0.w);
            af[4]=(short)f2bf(a1.x); af[5]=(short)f2bf(a1.y); af[6]=(short)f2bf(a1.z); af[7]=(short)f2bf(a1.w);
            acc0 = __builtin_amdgcn_mfma_f32_32x32x16_bf16(af, bf, acc0, 0, 0, 0);
        }
        {
            const int kcol = l31 + 32 * (2 * mh + 1);
            const float4 a0 = *(const float4*)(W + (size_t)kcol * FIN + c0);
            const float4 a1 = *(const float4*)(W + (size_t)kcol * FIN + c0 + 4);
            short8 af;
            af[0]=(short)f2bf(a0.x); af[1]=(short)f2bf(a0.y); af[2]=(short)f2bf(a0.z); af[3]=(short)f2bf(a0.w);
            af[4]=(short)f2bf(a1.x); af[5]=(short)f2bf(a1.y); af[6]=(short)f2bf(a1.z); af[7]=(short)f2bf(a1.w);
            acc1 = __builtin_amdgcn_mfma_f32_32x32x16_bf16(af, bf, acc1, 0, 0, 0);
        }
    }
    __shared__ float sred[4][32];
    __shared__ float tred[4][32];
    float sacc = 0.f, tacc = 0.f;
    const int jloc = nt * 32 + l31;
    const int ksb = jloc >> 4;
    const int lane_j = 32 * ((jloc >> 3) & 1);
    const int e = jloc & 7;
    #pragma unroll
    for (int m = 0; m < 2; ++m) {
        #pragma unroll
        for (int r = 0; r < 16; ++r) {
            const int kcol = 32 * (2 * mh + m) + 4 * l5 + (r & 3) + 8 * (r >> 2);
            const float hv = (m ? acc1[r] : acc0[r]) + Wb[kcol];
            const int fg = kcol >> 5;
            const int lane = (kcol & 31) + lane_j;
            hT3[((((size_t)bx * 4 + fg) * 4 + ksb) * 64 + lane) * 8 + e] = f2bf(hv);
            sacc += hv * aw[kcol];
            tacc += hv * aw[FOUT + kcol];
        }
    }
    sacc += __shfl_xor(sacc, 32);
    tacc += __shfl_xor(tacc, 32);
    if (l < 32) { sred[w][l] = sacc; tred[w][l] = tacc; }
    __syncthreads();
    if (mh == 0 && l < 32) {
        s_out[i] = sred[w][l] + sred[w + 1][l];
        t_out[i] = tred[w][l] + tred[w + 1][l] + ab[0];
    }
}

// ---------------------------------------------------------------------------
// Pass B (compute-only): masks preloaded from bm3 into 2 int4 registers per
// lane (32B; no LDS, no ballots, no main-loop barriers). exp -> bf16 -> MFMA
// with coalesced hT3 frags. Epilogue: cross-wave LDS reduce, coalesced writes.
// launch_bounds(256,3): proven no-spill (r6: VGPR 84 + 64 AGPR).
// ---------------------------------------------------------------------------
__global__ __launch_bounds__(256, 3)
void gat_pass_b(const u64* __restrict__ bm3, const unsigned short* __restrict__ hT3,
                const float* __restrict__ s_in, const float* __restrict__ t_in,
                float* __restrict__ numw, float* __restrict__ dpart) {
    __shared__ float red[FOUT * ROWS];       // 16 KB
    __shared__ float denb[4][ROWS];          // 512 B
    const int tid = threadIdx.x;
    const int wv = tid >> 6, l = tid & 63;
    const int l5 = l >> 5, l31 = l & 31;
    const int i0 = blockIdx.x * ROWS;
    const int chunk = blockIdx.y;
    const int jb = chunk * JC;
    const float si = s_in[i0 + l31];

    // masks for this lane's row (l31) and this wave's NWIN windows
    const u64* mbase = bm3 + ((size_t)(i0 >> 5) * NCH + chunk) * (32 * WPC)
                     + (size_t)l31 * WPC + wv * NWIN;
    const int4 Rm0 = ((const int4*)mbase)[0];
    const int4 Rm1 = ((const int4*)mbase)[1];

    f32x16 acc0 = {}, acc1 = {}, acc2 = {}, acc3 = {};
    float dacc = 0.f;

    #pragma unroll
    for (int w = 0; w < NWIN; ++w) {
        const int4 pair = (w >> 1) == 0 ? Rm0 : Rm1;
        const u64 myw = (w & 1)
            ? (((u64)(unsigned)pair.z) | (((u64)(unsigned)pair.w) << 32))
            : (((u64)(unsigned)pair.x) | (((u64)(unsigned)pair.y) << 32));
        const int win = wv * NWIN + w;
        const int jw = jb + win * 64;
        const int tile = jw >> 6;
        #pragma unroll
        for (int ks = 0; ks < 4; ++ks) {
            const int jsl = jw + ks * 16 + l5 * 8;
            const float4 t0 = *(const float4*)(t_in + jsl);
            const float4 t1 = *(const float4*)(t_in + jsl + 4);
            const u64 m = myw >> (ks * 4 + l5 * 2);
            short8 bf;
            float x, p;
            x = si + t0.x; x = fmaxf(x, 0.2f * x); p = __expf(x);
            p = ((m >> 0)  & 1ull) ? p : 0.f; dacc += p; bf[0] = (short)f2bf(p);
            x = si + t0.y; x = fmaxf(x, 0.2f * x); p = __expf(x);
            p = ((m >> 16) & 1ull) ? p : 0.f; dacc += p; bf[1] = (short)f2bf(p);
            x = si + t0.z; x = fmaxf(x, 0.2f * x); p = __expf(x);
            p = ((m >> 32) & 1ull) ? p : 0.f; dacc += p; bf[2] = (short)f2bf(p);
            x = si + t0.w; x = fmaxf(x, 0.2f * x); p = __expf(x);
            p = ((m >> 48) & 1ull) ? p : 0.f; dacc += p; bf[3] = (short)f2bf(p);
            x = si + t1.x; x = fmaxf(x, 0.2f * x); p = __expf(x);
            p = ((m >> 1)  & 1ull) ? p : 0.f; dacc += p; bf[4] = (short)f2bf(p);
            x = si + t1.y; x = fmaxf(x, 0.2f * x); p = __expf(x);
            p = ((m >> 17) & 1ull) ? p : 0.f; dacc += p; bf[5] = (short)f2bf(p);
            x = si + t1.z; x = fmaxf(x, 0.2f * x); p = __expf(x);
            p = ((m >> 33) & 1ull) ? p : 0.f; dacc += p; bf[6] = (short)f2bf(p);
            x = si + t1.w; x = fmaxf(x, 0.2f * x); p = __expf(x);
            p = ((m >> 49) & 1ull) ? p : 0.f; dacc += p; bf[7] = (short)f2bf(p);

            const unsigned short* hp =
                hT3 + (((size_t)tile * 4) * 4 + ks) * 512 + (size_t)l * 8;
            const short8 af0 = *(const short8*)(hp);
            const short8 af1 = *(const short8*)(hp + 2048);
            const short8 af2 = *(const short8*)(hp + 4096);
            const short8 af3 = *(const short8*)(hp + 6144);
            acc0 = __builtin_amdgcn_mfma_f32_32x32x16_bf16(af0, bf, acc0, 0, 0, 0);
            acc1 = __builtin_amdgcn_mfma_f32_32x32x16_bf16(af1, bf, acc1, 0, 0, 0);
            acc2 = __builtin_amdgcn_mfma_f32_32x32x16_bf16(af2, bf, acc2, 0, 0, 0);
            acc3 = __builtin_amdgcn_mfma_f32_32x32x16_bf16(af3, bf, acc3, 0, 0, 0);
        }
    }

    // ---------- epilogue: cross-wave reduction (j-split partials) ----------
    #pragma unroll
    for (int ph = 0; ph < 4; ++ph) {
        __syncthreads();
        if (wv == ph) {
            #pragma unroll
            for (int r = 0; r < 16; ++r) {
                const int fr = (r & 3) + 8 * (r >> 2) + 4 * l5;
                if (ph == 0) {
                    red[(fr     ) * ROWS + l31] = acc0[r];
                    red[(fr + 32) * ROWS + l31] = acc1[r];
                    red[(fr + 64) * ROWS + l31] = acc2[r];
                    red[(fr + 96) * ROWS + l31] = acc3[r];
                } else {
                    red[(fr     ) * ROWS + l31] += acc0[r];
                    red[(fr + 32) * ROWS + l31] += acc1[r];
                    red[(fr + 64) * ROWS + l31] += acc2[r];
                    red[(fr + 96) * ROWS + l31] += acc3[r];
                }
            }
        }
    }
    dacc += __shfl_xor(dacc, 32);
    if (l5 == 0) denb[wv][l31] = dacc;
    __syncthreads();

    float* nb = numw + (size_t)chunk * FOUT * NN;
    #pragma unroll
    for (int e = 0; e < 4; ++e) {
        const int f = e * 32 + (tid >> 3);
        const int io = (tid & 7) * 4;
        *(float4*)(nb + (size_t)f * NN + i0 + io) = *(const float4*)(red + f * ROWS + io);
    }
    if (tid < ROWS)
        dpart[(size_t)chunk * NN + i0 + tid] =
            denb[0][tid] + denb[1][tid] + denb[2][tid] + denb[3][tid];
}

// ---------------------------------------------------------------------------
// Pass C: out[i][f] = elu( sum_c numw[c][f][i] / sum_c dpart[c][i] )
// ---------------------------------------------------------------------------
__global__ __launch_bounds__(256)
void gat_reduce(const float* __restrict__ numw, const float* __restrict__ dpart,
                float* __restrict__ out, int nchunk) {
    __shared__ float tile[FOUT * 33];
    __shared__ float dent[32];
    const int t = threadIdx.x;
    const int i0 = blockIdx.x * 32;
    if (t < 32) {
        float d = 0.f;
        for (int c = 0; c < nchunk; ++c) d += dpart[(size_t)c * NN + i0 + t];
        dent[t] = d;
    }
    __syncthreads();
    #pragma unroll
    for (int e = 0; e < 4; ++e) {
        const int f = e * 32 + (t >> 3);
        const int io = (t & 7) * 4;
        float4 s = {0.f, 0.f, 0.f, 0.f};
        for (int c = 0; c < nchunk; ++c) {
            const float4 v = *(const float4*)(numw + ((size_t)c * FOUT + f) * NN + i0 + io);
            s.x += v.x; s.y += v.y; s.z += v.z; s.w += v.w;
        }
        float v;
        v = s.x / dent[io + 0]; tile[f * 33 + io + 0] = (v > 0.f) ? v : expm1f(v);
        v = s.y / dent[io + 1]; tile[f * 33 + io + 1] = (v > 0.f) ? v : expm1f(v);
        v = s.z / dent[io + 2]; tile[f * 33 + io + 2] = (v > 0.f) ? v : expm1f(v);
        v = s.w / dent[io + 3]; tile[f * 33 + io + 3] = (v > 0.f) ? v : expm1f(v);
    }
    __syncthreads();
    #pragma unroll
    for (int e = 0; e < 4; ++e) {
        const int row = (t >> 5) * 4 + e;
        const int fo = (t & 31) * 4;
        const float4 v = { tile[(fo + 0) * 33 + row], tile[(fo + 1) * 33 + row],
                           tile[(fo + 2) * 33 + row], tile[(fo + 3) * 33 + row] };
        *(float4*)(out + (size_t)(i0 + row) * FOUT + fo) = v;
    }
}

// ---------------------------------------------------------------------------
extern "C" void kernel_launch(void* const* d_in, const int* in_sizes, int n_in,
                              void* d_out, int out_size, void* d_ws, size_t ws_size,
                              hipStream_t stream) {
    const float* input = (const float*)d_in[0];
    const int*   adj   = (const int*)d_in[1];
    const float* Ww    = (const float*)d_in[2];
    const float* Wb    = (const float*)d_in[3];
    const float* aw    = (const float*)d_in[4];
    const float* ab    = (const float*)d_in[5];
    float* out = (float*)d_out;

    char* ws = (char*)d_ws;
    unsigned short* hT3 = (unsigned short*)ws;               // 2 MB
    float* s_buf = (float*)(ws + (size_t)FOUT * NN * 2);     // 32 KB
    float* t_buf = s_buf + NN;                               // 32 KB
    float* dpart = t_buf + NN;                               // NCH*32 KB
    float* numw = dpart + (size_t)NCH * NN;                  // NCH*4 MB
    u64* bm3 = (u64*)(numw + (size_t)NCH * NN * FOUT);       // 8 MB

    gat_pass_a<<<dim3(NN / 64), 256, 0, stream>>>(input, Ww, Wb, aw, ab, hT3, s_buf, t_buf);
    gat_compress<<<dim3(NN / 2), 256, 0, stream>>>(adj, bm3);
    gat_pass_b<<<dim3(NN / ROWS, NCH), 256, 0, stream>>>(bm3, hT3, s_buf, t_buf, numw, dpart);
    gat_reduce<<<dim3(NN / 32), 256, 0, stream>>>(numw, dpart, out, NCH);
}

// Round 10
// 153.123 us; speedup vs baseline: 2.1229x; 1.5426x over previous
//
#include <hip/hip_runtime.h>
#include <hip/hip_bf16.h>
#include <cmath>

#define NN 8192
#define FIN 256
#define FOUT 128
#define NCH 8
#define JC (NN / NCH)        // 1024 j per chunk
#define WPC (JC / 64)        // 16 windows per chunk
#define MPITCH 18            // LDS mask row pitch (u64), padded

typedef short short8 __attribute__((ext_vector_type(8)));
typedef float f32x16 __attribute__((ext_vector_type(16)));
typedef unsigned long long u64;

static __device__ __forceinline__ unsigned short f2bf(float f) {
    unsigned u = __float_as_uint(f);
    u += 0x7fffu + ((u >> 16) & 1u);
    return (unsigned short)(u >> 16);
}

// ---------------------------------------------------------------------------
// Compress: adj (256MB int32) -> bm3 (8MB u64), layout [chunk][row][winc]
// so each pass_b block stages a CONTIGUOUS 16KB slab. Word bit (16c+q) <->
// col (ch*16+winc)*64 + 4q + c. Each thread reads 256B contiguous.
// ---------------------------------------------------------------------------
__global__ __launch_bounds__(256)
void gat_compress(const int* __restrict__ adj, u64* __restrict__ bm3) {
    const int t = threadIdx.x;
    const int row = blockIdx.x * 2 + (t >> 7);
    const int wing = t & 127;                       // global window index
    const int4* p = (const int4*)(adj + (size_t)row * NN + wing * 64);
    u64 m = 0;
    #pragma unroll
    for (int q = 0; q < 16; ++q) {
        const int4 v = p[q];
        m |= (u64)(v.x > 0) << q;
        m |= (u64)(v.y > 0) << (16 + q);
        m |= (u64)(v.z > 0) << (32 + q);
        m |= (u64)(v.w > 0) << (48 + q);
    }
    const int ch = wing >> 4, winc = wing & 15;
    bm3[((size_t)ch * NN + row) * 16 + winc] = m;
}

// ---------------------------------------------------------------------------
// Pass A: h = input @ W^T + Wb (bf16 MFMA). Writes hT3 in EXACT MFMA A-frag
// order: hT3[tile][fg][ks][lane][e] = h[fg*32+(lane&31)][tile*64+ks*16+(lane>>5)*8+e]
// so pass_b frag loads are 64-lane-contiguous 1KB. Also s = h·a1, t = h·a2+ab.
// ---------------------------------------------------------------------------
__global__ __launch_bounds__(256, 2)
void gat_pass_a(const float* __restrict__ input, const float* __restrict__ W,
                const float* __restrict__ Wb, const float* __restrict__ aw,
                const float* __restrict__ ab, unsigned short* __restrict__ hT3,
                float* __restrict__ s_out, float* __restrict__ t_out) {
    const int tid = threadIdx.x;
    const int w = tid >> 6, l = tid & 63;
    const int l5 = l >> 5, l31 = l & 31;
    const int nt = w >> 1, mh = w & 1;
    const int bx = blockIdx.x;
    const int i = bx * 64 + nt * 32 + l31;

    f32x16 acc0 = {}; f32x16 acc1 = {};
    #pragma unroll
    for (int ks = 0; ks < FIN / 16; ++ks) {
        const int c0 = ks * 16 + l5 * 8;
        const float4 b0 = *(const float4*)(input + (size_t)i * FIN + c0);
        const float4 b1 = *(const float4*)(input + (size_t)i * FIN + c0 + 4);
        short8 bf;
        bf[0]=(short)f2bf(b0.x); bf[1]=(short)f2bf(b0.y); bf[2]=(short)f2bf(b0.z); bf[3]=(short)f2bf(b0.w);
        bf[4]=(short)f2bf(b1.x); bf[5]=(short)f2bf(b1.y); bf[6]=(short)f2bf(b1.z); bf[7]=(short)f2bf(b1.w);
        {
            const int kcol = l31 + 32 * (2 * mh + 0);
            const float4 a0 = *(const float4*)(W + (size_t)kcol * FIN + c0);
            const float4 a1 = *(const float4*)(W + (size_t)kcol * FIN + c0 + 4);
            short8 af;
            af[0]=(short)f2bf(a0.x); af[1]=(short)f2bf(a0.y); af[2]=(short)f2bf(a0.z); af[3]=(short)f2bf(a0.w);
            af[4]=(short)f2bf(a1.x); af[5]=(short)f2bf(a1.y); af[6]=(short)f2bf(a1.z); af[7]=(short)f2bf(a1.w);
            acc0 = __builtin_amdgcn_mfma_f32_32x32x16_bf16(af, bf, acc0, 0, 0, 0);
        }
        {
            const int kcol = l31 + 32 * (2 * mh + 1);
            const float4 a0 = *(const float4*)(W + (size_t)kcol * FIN + c0);
            const float4 a1 = *(const float4*)(W + (size_t)kcol * FIN + c0 + 4);
            short8 af;
            af[0]=(short)f2bf(a0.x); af[1]=(short)f2bf(a0.y); af[2]=(short)f2bf(a0.z); af[3]=(short)f2bf(a0.w);
            af[4]=(short)f2bf(a1.x); af[5]=(short)f2bf(a1.y); af[6]=(short)f2bf(a1.z); af[7]=(short)f2bf(a1.w);
            acc1 = __builtin_amdgcn_mfma_f32_32x32x16_bf16(af, bf, acc1, 0, 0, 0);
        }
    }
    __shared__ float sred[4][32];
    __shared__ float tred[4][32];
    float sacc = 0.f, tacc = 0.f;
    const int jloc = nt * 32 + l31;
    const int ksb = jloc >> 4;
    const int lane_j = 32 * ((jloc >> 3) & 1);
    const int e = jloc & 7;
    #pragma unroll
    for (int m = 0; m < 2; ++m) {
        #pragma unroll
        for (int r = 0; r < 16; ++r) {
            const int kcol = 32 * (2 * mh + m) + 4 * l5 + (r & 3) + 8 * (r >> 2);
            const float hv = (m ? acc1[r] : acc0[r]) + Wb[kcol];
            const int fg = kcol >> 5;
            const int lane = (kcol & 31) + lane_j;
            hT3[((((size_t)bx * 4 + fg) * 4 + ksb) * 64 + lane) * 8 + e] = f2bf(hv);
            sacc += hv * aw[kcol];
            tacc += hv * aw[FOUT + kcol];
        }
    }
    sacc += __shfl_xor(sacc, 32);
    tacc += __shfl_xor(tacc, 32);
    if (l < 32) { sred[w][l] = sacc; tred[w][l] = tacc; }
    __syncthreads();
    if (mh == 0 && l < 32) {
        s_out[i] = sred[w][l] + sred[w + 1][l];
        t_out[i] = tred[w][l] + tred[w + 1][l] + ab[0];
    }
}

// ---------------------------------------------------------------------------
// Pass B (barrier-free compute): block = 4 waves x 128 rows x one j-chunk.
// EACH WAVE OWNS 32 ROWS (no K-split) -> accumulators are complete chunk
// partials -> NO cross-wave reduction, NO phased epilogue. Masks staged once
// (16KB contiguous -> padded LDS), one barrier total. Direct coalesced stores.
// ---------------------------------------------------------------------------
__global__ __launch_bounds__(256, 2)
void gat_pass_b(const u64* __restrict__ bm3, const unsigned short* __restrict__ hT3,
                const float* __restrict__ s_in, const float* __restrict__ t_in,
                float* __restrict__ numw, float* __restrict__ dpart) {
    __shared__ u64 mlds[128 * MPITCH];       // 18 KB
    const int tid = threadIdx.x;
    const int wv = tid >> 6, l = tid & 63;
    const int l5 = l >> 5, l31 = l & 31;
    const int i0 = blockIdx.x * 128;
    const int chunk = blockIdx.y;
    const int jb = chunk * JC;

    // ---- stage masks: 16KB contiguous -> LDS [128][18] (one barrier) ----
    {
        const uint4* src = (const uint4*)(bm3 + ((size_t)chunk * NN + i0) * 16) + tid * 4;
        const uint4 a0 = src[0], a1 = src[1], a2 = src[2], a3 = src[3];
        u64* dst = mlds + (tid >> 1) * MPITCH + (tid & 1) * 8;
        *(uint4*)(dst)     = a0;
        *(uint4*)(dst + 2) = a1;
        *(uint4*)(dst + 4) = a2;
        *(uint4*)(dst + 6) = a3;
    }
    const int lrow = wv * 32 + l31;          // this lane's row (local)
    const float si = s_in[i0 + lrow];
    __syncthreads();

    f32x16 acc0 = {}, acc1 = {}, acc2 = {}, acc3 = {};
    float dacc = 0.f;

    #pragma unroll 2
    for (int win = 0; win < WPC; ++win) {
        const u64 myw = mlds[lrow * MPITCH + win];
        const int jw = jb + win * 64;
        const int tile = jw >> 6;
        #pragma unroll
        for (int ks = 0; ks < 4; ++ks) {
            const int jsl = jw + ks * 16 + l5 * 8;
            const float4 t0 = *(const float4*)(t_in + jsl);
            const float4 t1 = *(const float4*)(t_in + jsl + 4);
            const u64 m = myw >> (ks * 4 + l5 * 2);
            short8 bf;
            float x, p;
            x = si + t0.x; x = fmaxf(x, 0.2f * x); p = __expf(x);
            p = ((m >> 0)  & 1ull) ? p : 0.f; dacc += p; bf[0] = (short)f2bf(p);
            x = si + t0.y; x = fmaxf(x, 0.2f * x); p = __expf(x);
            p = ((m >> 16) & 1ull) ? p : 0.f; dacc += p; bf[1] = (short)f2bf(p);
            x = si + t0.z; x = fmaxf(x, 0.2f * x); p = __expf(x);
            p = ((m >> 32) & 1ull) ? p : 0.f; dacc += p; bf[2] = (short)f2bf(p);
            x = si + t0.w; x = fmaxf(x, 0.2f * x); p = __expf(x);
            p = ((m >> 48) & 1ull) ? p : 0.f; dacc += p; bf[3] = (short)f2bf(p);
            x = si + t1.x; x = fmaxf(x, 0.2f * x); p = __expf(x);
            p = ((m >> 1)  & 1ull) ? p : 0.f; dacc += p; bf[4] = (short)f2bf(p);
            x = si + t1.y; x = fmaxf(x, 0.2f * x); p = __expf(x);
            p = ((m >> 17) & 1ull) ? p : 0.f; dacc += p; bf[5] = (short)f2bf(p);
            x = si + t1.z; x = fmaxf(x, 0.2f * x); p = __expf(x);
            p = ((m >> 33) & 1ull) ? p : 0.f; dacc += p; bf[6] = (short)f2bf(p);
            x = si + t1.w; x = fmaxf(x, 0.2f * x); p = __expf(x);
            p = ((m >> 49) & 1ull) ? p : 0.f; dacc += p; bf[7] = (short)f2bf(p);

            const unsigned short* hp =
                hT3 + ((size_t)tile * 16 + ks) * 512 + (size_t)l * 8;
            const short8 af0 = *(const short8*)(hp);
            const short8 af1 = *(const short8*)(hp + 2048);
            const short8 af2 = *(const short8*)(hp + 4096);
            const short8 af3 = *(const short8*)(hp + 6144);
            acc0 = __builtin_amdgcn_mfma_f32_32x32x16_bf16(af0, bf, acc0, 0, 0, 0);
            acc1 = __builtin_amdgcn_mfma_f32_32x32x16_bf16(af1, bf, acc1, 0, 0, 0);
            acc2 = __builtin_amdgcn_mfma_f32_32x32x16_bf16(af2, bf, acc2, 0, 0, 0);
            acc3 = __builtin_amdgcn_mfma_f32_32x32x16_bf16(af3, bf, acc3, 0, 0, 0);
        }
    }

    // ---- epilogue: direct coalesced stores (no reduction, no barrier) ----
    float* nb = numw + (size_t)chunk * FOUT * NN;
    const int irow = i0 + lrow;
    #pragma unroll
    for (int r = 0; r < 16; ++r) {
        const int fr = (r & 3) + 8 * (r >> 2) + 4 * l5;
        nb[(size_t)(fr      ) * NN + irow] = acc0[r];
        nb[(size_t)(fr +  32) * NN + irow] = acc1[r];
        nb[(size_t)(fr +  64) * NN + irow] = acc2[r];
        nb[(size_t)(fr +  96) * NN + irow] = acc3[r];
    }
    dacc += __shfl_xor(dacc, 32);
    if (l5 == 0) dpart[(size_t)chunk * NN + irow] = dacc;
}

// ---------------------------------------------------------------------------
// Pass C: out[i][f] = elu( sum_c numw[c][f][i] / sum_c dpart[c][i] )
// ---------------------------------------------------------------------------
__global__ __launch_bounds__(256)
void gat_reduce(const float* __restrict__ numw, const float* __restrict__ dpart,
                float* __restrict__ out, int nchunk) {
    __shared__ float tile[FOUT * 33];
    __shared__ float dent[32];
    const int t = threadIdx.x;
    const int i0 = blockIdx.x * 32;
    if (t < 32) {
        float d = 0.f;
        for (int c = 0; c < nchunk; ++c) d += dpart[(size_t)c * NN + i0 + t];
        dent[t] = d;
    }
    __syncthreads();
    #pragma unroll
    for (int e = 0; e < 4; ++e) {
        const int f = e * 32 + (t >> 3);
        const int io = (t & 7) * 4;
        float4 s = {0.f, 0.f, 0.f, 0.f};
        for (int c = 0; c < nchunk; ++c) {
            const float4 v = *(const float4*)(numw + ((size_t)c * FOUT + f) * NN + i0 + io);
            s.x += v.x; s.y += v.y; s.z += v.z; s.w += v.w;
        }
        float v;
        v = s.x / dent[io + 0]; tile[f * 33 + io + 0] = (v > 0.f) ? v : expm1f(v);
        v = s.y / dent[io + 1]; tile[f * 33 + io + 1] = (v > 0.f) ? v : expm1f(v);
        v = s.z / dent[io + 2]; tile[f * 33 + io + 2] = (v > 0.f) ? v : expm1f(v);
        v = s.w / dent[io + 3]; tile[f * 33 + io + 3] = (v > 0.f) ? v : expm1f(v);
    }
    __syncthreads();
    #pragma unroll
    for (int e = 0; e < 4; ++e) {
        const int row = (t >> 5) * 4 + e;
        const int fo = (t & 31) * 4;
        const float4 v = { tile[(fo + 0) * 33 + row], tile[(fo + 1) * 33 + row],
                           tile[(fo + 2) * 33 + row], tile[(fo + 3) * 33 + row] };
        *(float4*)(out + (size_t)(i0 + row) * FOUT + fo) = v;
    }
}

// ---------------------------------------------------------------------------
extern "C" void kernel_launch(void* const* d_in, const int* in_sizes, int n_in,
                              void* d_out, int out_size, void* d_ws, size_t ws_size,
                              hipStream_t stream) {
    const float* input = (const float*)d_in[0];
    const int*   adj   = (const int*)d_in[1];
    const float* Ww    = (const float*)d_in[2];
    const float* Wb    = (const float*)d_in[3];
    const float* aw    = (const float*)d_in[4];
    const float* ab    = (const float*)d_in[5];
    float* out = (float*)d_out;

    char* ws = (char*)d_ws;
    unsigned short* hT3 = (unsigned short*)ws;               // 2 MB
    float* s_buf = (float*)(ws + (size_t)FOUT * NN * 2);     // 32 KB
    float* t_buf = s_buf + NN;                               // 32 KB
    float* dpart = t_buf + NN;                               // NCH*32 KB
    float* numw = dpart + (size_t)NCH * NN;                  // NCH*4 MB
    u64* bm3 = (u64*)(numw + (size_t)NCH * NN * FOUT);       // 8 MB

    gat_pass_a<<<dim3(NN / 64), 256, 0, stream>>>(input, Ww, Wb, aw, ab, hT3, s_buf, t_buf);
    gat_compress<<<dim3(NN / 2), 256, 0, stream>>>(adj, bm3);
    gat_pass_b<<<dim3(NN / 128, NCH), 256, 0, stream>>>(bm3, hT3, s_buf, t_buf, numw, dpart);
    gat_reduce<<<dim3(NN / 32), 256, 0, stream>>>(numw, dpart, out, NCH);
}